// Round 16
// baseline (156.450 us; speedup 1.0000x reference)
//
#include <hip/hip_runtime.h>

#define B_ 4
#define N_ 325
#define I_ 64
#define H_ 128
#define NODES (B_ * N_)
#define NZMAX 64                    // max nz/row ~35 (5% of 325 + self-loop)
#define LSTMB 325                   // LSTM blocks in k1
#define K1GRID (LSTMB + 17)         // + 16 transpose blocks + 1 svec block

typedef unsigned short u16;
typedef unsigned int u32;

// weight scratch for k2/k3, written by k1's rider blocks each launch.
__device__ __align__(16) float g_WsT  [128 * 128];   // [k][o]
__device__ __align__(16) float g_WtT  [128 * 128];   // [k][o]
__device__ __align__(16) float g_combT[256 * 128];   // [k][o]
__device__ float g_svec[896];  // [0]=gc_b [128]=Ws_b [256]=Wt_b [384]=v [512]=ln_g [640]=ln_b [768]=comb_b

// activation scratch
__device__ __align__(16) float g_support[(size_t)NODES * H_];
__device__ __align__(16) float g_h_graph[(size_t)NODES * H_];
__device__ __align__(16) float g_s_buf  [(size_t)NODES * H_];
__device__ __align__(16) float g_t_buf  [(size_t)NODES * H_];
__device__ __align__(16) float g_hl     [(size_t)NODES * H_];
__device__ u16 g_nz [(size_t)NODES * NZMAX];
__device__ int g_nzc[NODES];

__device__ __forceinline__ float bf2f(u16 u) { return __uint_as_float(((u32)u) << 16); }
__device__ __forceinline__ float lo16(u32 u) { return __uint_as_float(u << 16); }
__device__ __forceinline__ float hi16(u32 u) { return __uint_as_float(u & 0xffff0000u); }
__device__ __forceinline__ u16 f2bf(float f) {
    u32 u = __float_as_uint(f);
    u += 0x7fffu + ((u >> 16) & 1u);   // RNE
    return (u16)(u >> 16);
}
__device__ __forceinline__ float ldin(const void* p, size_t i, int f32) {
    return f32 ? ((const float*)p)[i] : bf2f(((const u16*)p)[i]);
}
__device__ __forceinline__ void stout(void* p, size_t i, float v, int f32) {
    if (f32) ((float*)p)[i] = v; else ((u16*)p)[i] = f2bf(v);
}
__device__ __forceinline__ float fast_rcp(float x) { return __builtin_amdgcn_rcpf(x); }
__device__ __forceinline__ float sigm(float x) { return fast_rcp(1.f + __expf(-x)); }
__device__ __forceinline__ float tanh_f(float x) {
    x = fminf(15.f, fmaxf(-15.f, x));
    float e = __expf(2.f * x);
    return (e - 1.f) * fast_rcp(e + 1.f);
}
// adj[0,0]==1.0 (self-loop): fp32 low16 = 0x0000, bf16 low16 = 0x3F80.
__device__ __forceinline__ int probe_f32(const void* adj) {
    return ((((const u32*)adj)[0] & 0xFFFFu) != 0x3F80u) ? 1 : 0;
}

// ---------------------------------------------------------------------------
// K1: blocks 0..324: LSTM (gates via in-LDS transposed W chunks, cell,
// support). Blocks 325..340: tile-transpose Ws/Wt/comb for k2/k3.
// Block 341: svec gather. 512 threads each.
// ---------------------------------------------------------------------------
__global__ __launch_bounds__(512) void k1_lstm(
    const void* __restrict__ x, const void* __restrict__ h, const void* __restrict__ c,
    const void* __restrict__ W_ih, const void* __restrict__ W_hh,
    const void* __restrict__ b_ih, const void* __restrict__ b_hh,
    const void* __restrict__ gc_w, const void* __restrict__ gc_b,
    const void* __restrict__ Ws_w, const void* __restrict__ Ws_b,
    const void* __restrict__ Wt_w, const void* __restrict__ Wt_b,
    const void* __restrict__ vvec, const void* __restrict__ ln_g,
    const void* __restrict__ ln_b, const void* __restrict__ comb_w,
    const void* __restrict__ comb_b, const void* __restrict__ adj,
    void* __restrict__ out)
{
    const int f32 = probe_f32(adj);
    __shared__ float WTs[32][513];               // 65,664 B; also reused as tile
    __shared__ __align__(16) float4 xh4[192];    // [k] x {n0..n3}
    __shared__ __align__(16) float4 Gt4[512];    // [g] x {n0..n3}
    __shared__ __align__(16) float4 hl4[128];    // [k] x {n0..n3}
    const int t = threadIdx.x;

    if (blockIdx.x >= LSTMB) {
        const int b2 = blockIdx.x - LSTMB;
        if (b2 < 16) {
            // 64x64 tile transposes (coalesced both ways, padded LDS)
            float (*tile)[65] = reinterpret_cast<float (*)[65]>(&WTs[0][0]);
            const void* src; float* dst; int C, r0, c0;
            if (b2 < 4)       { src = Ws_w;   dst = g_WsT;   C = 128; r0 = (b2 >> 1) * 64;        c0 = (b2 & 1) * 64; }
            else if (b2 < 8)  { int i = b2 - 4; src = Wt_w;   dst = g_WtT;   C = 128; r0 = (i >> 1) * 64; c0 = (i & 1) * 64; }
            else              { int i = b2 - 8; src = comb_w; dst = g_combT; C = 256; r0 = (i >> 2) * 64; c0 = (i & 3) * 64; }
            const int lane = t & 63, wv = t >> 6;
            for (int rr = wv; rr < 64; rr += 8)
                tile[rr][lane] = ldin(src, (size_t)(r0 + rr) * C + c0 + lane, f32);
            __syncthreads();
            for (int cc = wv; cc < 64; cc += 8)
                dst[(size_t)(c0 + cc) * 128 + r0 + lane] = tile[lane][cc];
        } else {
            for (int e = t; e < 896; e += 512) {
                const int seg = e >> 7, k = e & 127;
                const void* s = (seg == 0) ? gc_b : (seg == 1) ? Ws_b : (seg == 2) ? Wt_b :
                                (seg == 3) ? vvec : (seg == 4) ? ln_g : (seg == 5) ? ln_b : comb_b;
                g_svec[e] = ldin(s, k, f32);
            }
        }
        return;
    }

    // ---------------- LSTM block ----------------
    const int node0 = blockIdx.x * 4;

    // stage activations [k] x {n}
    for (int e = t; e < 768; e += 512) {
        const int n = e / 192, k = e % 192;
        const int node = node0 + n;
        ((float*)&xh4[k])[n] = (k < 64) ? ldin(x, (size_t)node * 64 + k, f32)
                                        : ldin(h, (size_t)node * 128 + (k - 64), f32);
    }

    // gates: thread t owns gate row g=t; W staged transposed in LDS chunks
    float a0 = 0.f, a1 = 0.f, a2 = 0.f, a3 = 0.f;
    for (int cch = 0; cch < 6; ++cch) {
        const int k0 = cch * 32;
        __syncthreads();   // protect WTs (and, on cch==0, publish xh4)
        if (f32) {
            const float* src = (cch < 2) ? ((const float*)W_ih + (size_t)t * 64 + k0)
                                         : ((const float*)W_hh + (size_t)t * 128 + (k0 - 64));
            #pragma unroll
            for (int j = 0; j < 16; ++j) {       // 8B loads (alignment law)
                const float2 v = ((const float2*)src)[j];
                WTs[j * 2][t]     = v.x;
                WTs[j * 2 + 1][t] = v.y;
            }
        } else {
            const u16* src = (cch < 2) ? ((const u16*)W_ih + (size_t)t * 64 + k0)
                                       : ((const u16*)W_hh + (size_t)t * 128 + (k0 - 64));
            #pragma unroll
            for (int j = 0; j < 8; ++j) {        // uint2 = 4 bf16
                const uint2 v = ((const uint2*)src)[j];
                WTs[j * 4 + 0][t] = lo16(v.x); WTs[j * 4 + 1][t] = hi16(v.x);
                WTs[j * 4 + 2][t] = lo16(v.y); WTs[j * 4 + 3][t] = hi16(v.y);
            }
        }
        __syncthreads();
        #pragma unroll
        for (int kk = 0; kk < 32; ++kk) {
            const float wv = WTs[kk][t];
            const float4 xv = xh4[k0 + kk];
            a0 = fmaf(xv.x, wv, a0); a1 = fmaf(xv.y, wv, a1);
            a2 = fmaf(xv.z, wv, a2); a3 = fmaf(xv.w, wv, a3);
        }
    }
    {
        const float bias = ldin(b_ih, t, f32) + ldin(b_hh, t, f32);
        Gt4[t] = make_float4(a0 + bias, a1 + bias, a2 + bias, a3 + bias);
    }
    __syncthreads();

    // cell nonlinearity: t = (n, hh)
    {
        const int n = t >> 7, hh = t & 127;
        const int node = node0 + n;
        const float ig = ((const float*)&Gt4[hh])[n];
        const float fg = ((const float*)&Gt4[128 + hh])[n];
        const float gv = ((const float*)&Gt4[256 + hh])[n];
        const float og = ((const float*)&Gt4[384 + hh])[n];
        const float cl = sigm(fg) * ldin(c, (size_t)node * 128 + hh, f32) + sigm(ig) * tanh_f(gv);
        const float hv = sigm(og) * tanh_f(cl);
        stout(out, (size_t)(NODES * H_) + (size_t)node * 128 + hh, cl, f32);
        g_hl[(size_t)node * 128 + hh] = hv;
        ((float*)&hl4[hh])[n] = hv;
    }
    __syncthreads();

    // support[n][o] = sum_k hl[n][k] * gc_w[k][o]  (direct reads, coalesced)
    {
        const int o = t & 127, n = t >> 7;       // n wave-uniform
        float acc = 0.f;
        if (f32) {
            const float* G = (const float*)gc_w;
            #pragma unroll 8
            for (int k = 0; k < 128; ++k)
                acc = fmaf(((const float*)&hl4[k])[n], G[(size_t)k * 128 + o], acc);
        } else {
            const u16* G = (const u16*)gc_w;
            #pragma unroll 8
            for (int k = 0; k < 128; ++k)
                acc = fmaf(((const float*)&hl4[k])[n], bf2f(G[(size_t)k * 128 + o]), acc);
        }
        g_support[(size_t)(node0 + n) * 128 + o] = acc;
    }
}

// ---------------------------------------------------------------------------
// K2: 325 blocks x 256 threads, 4 nodes/block. nz compaction + gather + s/t.
// ---------------------------------------------------------------------------
__global__ __launch_bounds__(256) void k2_graph(const void* __restrict__ adj)
{
    const int f32 = probe_f32(adj);
    __shared__ __align__(16) float4 hg4[128];    // [k] x {n0..n3}
    __shared__ u16 nzi[4][NZMAX];
    __shared__ float nzv[4][NZMAX];
    __shared__ int cnt[4];
    const int node0 = blockIdx.x * 4;
    const int t = threadIdx.x;
    const int lane = t & 63, w = t >> 6;

    if (t < 4) cnt[t] = 0;
    __syncthreads();
    for (int j = lane; j < N_; j += 64) {        // wave w compacts node node0+w
        float a = ldin(adj, (size_t)(node0 + w) * N_ + j, f32);
        if (a != 0.f) {
            int p = atomicAdd(&cnt[w], 1);
            if (p < NZMAX) { nzi[w][p] = (u16)j; nzv[w][p] = a; }
        }
    }
    __syncthreads();
    if (t < 4) g_nzc[node0 + t] = min(cnt[t], NZMAX);
    #pragma unroll
    for (int n = 0; n < 4; ++n) {
        const int cnn = min(cnt[n], NZMAX);
        for (int p = t; p < cnn; p += 256) g_nz[(size_t)(node0 + n) * NZMAX + p] = nzi[n][p];
    }

    // h_graph gather: dual accumulators (even/odd p)
    const int o = t & 127;
    const float gb = g_svec[o];                  // gc_b
    #pragma unroll
    for (int ps = 0; ps < 2; ++ps) {
        const int n = (t >> 7) + 2 * ps;
        const int node = node0 + n;
        const int bn = node / N_;
        const int cnn = min(cnt[n], NZMAX);
        float accA = 0.f, accB = 0.f;
        int p = 0;
        for (; p + 1 < cnn; p += 2) {
            accA = fmaf(nzv[n][p],     g_support[((size_t)bn * N_ + nzi[n][p])     * 128 + o], accA);
            accB = fmaf(nzv[n][p + 1], g_support[((size_t)bn * N_ + nzi[n][p + 1]) * 128 + o], accB);
        }
        if (p < cnn)
            accA = fmaf(nzv[n][p], g_support[((size_t)bn * N_ + nzi[n][p]) * 128 + o], accA);
        const float acc = accA + accB + gb;
        g_h_graph[(size_t)node * 128 + o] = acc;
        ((float*)&hg4[o])[n] = acc;
    }
    __syncthreads();

    // s (t<128) / t (t>=128) projections: coalesced W^T, broadcast hg
    {
        const int which = t >> 7;
        const float* WT = which ? g_WtT : g_WsT;
        const float bias = g_svec[128 + which * 128 + o];
        float a0 = 0.f, a1 = 0.f, a2 = 0.f, a3 = 0.f;
        #pragma unroll 8
        for (int k = 0; k < 128; ++k) {
            const float wv = WT[(size_t)k * 128 + o];
            const float4 hv = hg4[k];
            a0 = fmaf(hv.x, wv, a0); a1 = fmaf(hv.y, wv, a1);
            a2 = fmaf(hv.z, wv, a2); a3 = fmaf(hv.w, wv, a3);
        }
        float* dst = which ? g_t_buf : g_s_buf;
        dst[(size_t)(node0 + 0) * 128 + o] = a0 + bias;
        dst[(size_t)(node0 + 1) * 128 + o] = a1 + bias;
        dst[(size_t)(node0 + 2) * 128 + o] = a2 + bias;
        dst[(size_t)(node0 + 3) * 128 + o] = a3 + bias;
    }
}

// ---------------------------------------------------------------------------
// K3: 325 blocks x 256 threads, 4 nodes/block. scores+softmax+ctx+LN+combine.
// ---------------------------------------------------------------------------
__global__ __launch_bounds__(256) void k3_attn(
    const void* __restrict__ adj, void* __restrict__ out)
{
    const int f32 = probe_f32(adj);
    __shared__ __align__(16) float4 comb4[256];  // [k] x {n0..n3}: [h_lstm | h_att]
    __shared__ float s_i[4][H_];
    __shared__ float red[4][H_];
    __shared__ float nzs[4][NZMAX];
    __shared__ u16 nzi[4][NZMAX];
    __shared__ float part[2][4][H_];
    __shared__ float mu_[4], rstd_[4], smv[4];
    __shared__ int cnt[4];
    const int node0 = blockIdx.x * 4;
    const int t = threadIdx.x;
    const int lane = t & 63, w = t >> 6;

    if (t < 4) cnt[t] = g_nzc[node0 + t];
    for (int e = t; e < 512; e += 256) {
        const int n = e >> 7, k = e & 127;
        const int node = node0 + n;
        s_i[n][k] = g_s_buf[(size_t)node * 128 + k];
        ((float*)&comb4[k])[n] = g_hl[(size_t)node * 128 + k];
    }
    __syncthreads();
    #pragma unroll
    for (int n = 0; n < 4; ++n)
        for (int p = t; p < cnt[n]; p += 256) nzi[n][p] = g_nz[(size_t)(node0 + n) * NZMAX + p];
    __syncthreads();

    // scores: wave w owns node node0+w; half-wave per neighbor (2 p / iter)
    {
        const int bn = (node0 + w) / N_;
        const int cn = cnt[w];
        const int sl = lane & 31, hf = lane >> 5;
        const float v0 = g_svec[384 + sl],      v1 = g_svec[384 + 32 + sl];
        const float v2 = g_svec[384 + 64 + sl], v3 = g_svec[384 + 96 + sl];
        const float s0 = s_i[w][sl],      s1 = s_i[w][sl + 32];
        const float s2 = s_i[w][sl + 64], s3 = s_i[w][sl + 96];
        for (int base = 0; base < cn; base += 2) {
            const int p = base + hf;
            float a = 0.f;
            if (p < cn) {
                const float* tj = g_t_buf + ((size_t)bn * N_ + nzi[w][p]) * 128;
                a = v0 * tanh_f(s0 + tj[sl])      + v1 * tanh_f(s1 + tj[sl + 32])
                  + v2 * tanh_f(s2 + tj[sl + 64]) + v3 * tanh_f(s3 + tj[sl + 96]);
            }
            a += __shfl_xor(a, 16); a += __shfl_xor(a, 8);
            a += __shfl_xor(a, 4);  a += __shfl_xor(a, 2); a += __shfl_xor(a, 1);
            if (sl == 0 && p < cn) nzs[w][p] = a;
        }
    }
    __syncthreads();

    if (t < 4) {                                 // softmax (serial, ~17-35)
        const int cn = cnt[t];
        float m = -1e30f;
        for (int p = 0; p < cn; ++p) m = fmaxf(m, nzs[t][p]);
        float ssum = 0.f;
        for (int p = 0; p < cn; ++p) { float e = __expf(nzs[t][p] - m); nzs[t][p] = e; ssum += e; }
        smv[t] = fast_rcp(ssum);
    }
    __syncthreads();

    // context: dual accumulators (even/odd p)
    const int o = t & 127;
    #pragma unroll
    for (int ps = 0; ps < 2; ++ps) {
        const int n = (t >> 7) + 2 * ps;
        const int bn = (node0 + n) / N_;
        const int cn = cnt[n];
        float accA = 0.f, accB = 0.f;
        int p = 0;
        for (; p + 1 < cn; p += 2) {
            accA = fmaf(nzs[n][p],     g_h_graph[((size_t)bn * N_ + nzi[n][p])     * 128 + o], accA);
            accB = fmaf(nzs[n][p + 1], g_h_graph[((size_t)bn * N_ + nzi[n][p + 1]) * 128 + o], accB);
        }
        if (p < cn)
            accA = fmaf(nzs[n][p], g_h_graph[((size_t)bn * N_ + nzi[n][p]) * 128 + o], accA);
        red[n][o] = (accA + accB) * smv[n];
    }
    __syncthreads();

    // LayerNorm stats: wave w -> node w
    {
        float x0 = red[w][lane], x1 = red[w][lane + 64];
        float sm = x0 + x1, sq = x0 * x0 + x1 * x1;
        #pragma unroll
        for (int off = 32; off > 0; off >>= 1) {
            sm += __shfl_xor(sm, off);
            sq += __shfl_xor(sq, off);
        }
        if (lane == 0) {
            float mu = sm * (1.f / H_);
            float var = fmaxf(sq * (1.f / H_) - mu * mu, 0.f);
            mu_[w] = mu;
            rstd_[w] = __builtin_amdgcn_rsqf(var + 1e-5f);
        }
    }
    __syncthreads();
    for (int e = t; e < 512; e += 256) {
        const int n = e >> 7, k = e & 127;
        float xn = (red[n][k] - mu_[n]) * rstd_[n];
        ((float*)&comb4[128 + k])[n] = g_svec[512 + k] * xn + g_svec[640 + k];
    }
    __syncthreads();

    // combine: coalesced combT, broadcast comb4; k split over halves
    {
        const int half = t >> 7;
        float a0 = 0.f, a1 = 0.f, a2 = 0.f, a3 = 0.f;
        const int k0 = half * 128;
        #pragma unroll 8
        for (int kk = 0; kk < 128; ++kk) {
            const float wv = g_combT[(size_t)(k0 + kk) * 128 + o];
            const float4 cv = comb4[k0 + kk];
            a0 = fmaf(cv.x, wv, a0); a1 = fmaf(cv.y, wv, a1);
            a2 = fmaf(cv.z, wv, a2); a3 = fmaf(cv.w, wv, a3);
        }
        part[half][0][o] = a0; part[half][1][o] = a1;
        part[half][2][o] = a2; part[half][3][o] = a3;
    }
    __syncthreads();
    for (int e = t; e < 512; e += 256) {
        const int n = e >> 7, k = e & 127;
        stout(out, (size_t)(node0 + n) * 128 + k,
              part[0][n][k] + part[1][n][k] + g_svec[768 + k], f32);
    }
}

// ---------------------------------------------------------------------------
extern "C" void kernel_launch(void* const* d_in, const int* in_sizes, int n_in,
                              void* d_out, int out_size, void* d_ws, size_t ws_size,
                              hipStream_t stream)
{
    (void)in_sizes; (void)n_in; (void)out_size; (void)d_ws; (void)ws_size;
    const void* x      = d_in[0];
    const void* adj    = d_in[1];
    const void* h      = d_in[2];
    const void* c      = d_in[3];
    const void* W_ih   = d_in[4];
    const void* W_hh   = d_in[5];
    const void* b_ih   = d_in[6];
    const void* b_hh   = d_in[7];
    const void* gc_w   = d_in[8];
    const void* gc_b   = d_in[9];
    const void* Ws_w   = d_in[10];
    const void* Ws_b   = d_in[11];
    const void* Wt_w   = d_in[12];
    const void* Wt_b   = d_in[13];
    const void* vvec   = d_in[14];
    const void* ln_g   = d_in[15];
    const void* ln_b   = d_in[16];
    const void* comb_w = d_in[17];
    const void* comb_b = d_in[18];

    k1_lstm <<<K1GRID, 512, 0, stream>>>(x, h, c, W_ih, W_hh, b_ih, b_hh,
                                         gc_w, gc_b, Ws_w, Ws_b, Wt_w, Wt_b,
                                         vvec, ln_g, ln_b, comb_w, comb_b,
                                         adj, d_out);
    k2_graph<<<NODES / 4, 256, 0, stream>>>(adj);
    k3_attn <<<NODES / 4, 256, 0, stream>>>(adj, d_out);
}

// Round 17
// 152.960 us; speedup vs baseline: 1.0228x; 1.0228x over previous
//
#include <hip/hip_runtime.h>

#define B_ 4
#define N_ 325
#define I_ 64
#define H_ 128
#define NODES (B_ * N_)
#define NZMAX 64                    // max nz/row ~35 (5% of 325 + self-loop)
#define NBLK (NODES / 4)            // 325 blocks, 4 nodes each

typedef unsigned short u16;
typedef unsigned int u32;

// f32 weight scratch, written by k0_prep each launch (converts + transposes).
__device__ __align__(16) float g_WT   [192 * 512];   // [k][g]  gates weights
__device__ __align__(16) float g_gcw  [128 * 128];   // [k][o]
__device__ __align__(16) float g_WsT  [128 * 128];   // [k][o]
__device__ __align__(16) float g_WtT  [128 * 128];   // [k][o]
__device__ __align__(16) float g_combT[256 * 128];   // [k][o]
__device__ float g_bias[512];                        // b_ih + b_hh
__device__ float g_svec[896];  // [0]=gc_b [128]=Ws_b [256]=Wt_b [384]=v [512]=ln_g [640]=ln_b [768]=comb_b

// activation scratch
__device__ __align__(16) float g_support[(size_t)NODES * H_];
__device__ __align__(16) float g_h_graph[(size_t)NODES * H_];
__device__ __align__(16) float g_s_buf  [(size_t)NODES * H_];
__device__ __align__(16) float g_t_buf  [(size_t)NODES * H_];
__device__ __align__(16) float g_hl     [(size_t)NODES * H_];
__device__ u16 g_nz [(size_t)NODES * NZMAX];
__device__ int g_nzc[NODES];

__device__ __forceinline__ float bf2f(u16 u) { return __uint_as_float(((u32)u) << 16); }
__device__ __forceinline__ u16 f2bf(float f) {
    u32 u = __float_as_uint(f);
    u += 0x7fffu + ((u >> 16) & 1u);   // RNE
    return (u16)(u >> 16);
}
__device__ __forceinline__ float ldin(const void* p, size_t i, int f32) {
    return f32 ? ((const float*)p)[i] : bf2f(((const u16*)p)[i]);
}
__device__ __forceinline__ void stout(void* p, size_t i, float v, int f32) {
    if (f32) ((float*)p)[i] = v; else ((u16*)p)[i] = f2bf(v);
}
__device__ __forceinline__ float fast_rcp(float x) { return __builtin_amdgcn_rcpf(x); }
__device__ __forceinline__ float sigm(float x) { return fast_rcp(1.f + __expf(-x)); }
__device__ __forceinline__ float tanh_f(float x) {
    x = fminf(15.f, fmaxf(-15.f, x));
    float e = __expf(2.f * x);
    return (e - 1.f) * fast_rcp(e + 1.f);
}
// adj[0,0]==1.0 (self-loop): fp32 low16 = 0x0000, bf16 low16 = 0x3F80.
__device__ __forceinline__ int probe_f32(const void* adj) {
    return ((((const u32*)adj)[0] & 0xFFFFu) != 0x3F80u) ? 1 : 0;
}

// ---------------------------------------------------------------------------
// K0: convert + transpose all weights/biases to f32 scratch (R12 version).
// ---------------------------------------------------------------------------
__global__ __launch_bounds__(256) void k0_prep(
    const void* __restrict__ W_ih, const void* __restrict__ W_hh,
    const void* __restrict__ b_ih, const void* __restrict__ b_hh,
    const void* __restrict__ gc_w, const void* __restrict__ gc_b,
    const void* __restrict__ Ws_w, const void* __restrict__ Ws_b,
    const void* __restrict__ Wt_w, const void* __restrict__ Wt_b,
    const void* __restrict__ vvec, const void* __restrict__ ln_g,
    const void* __restrict__ ln_b, const void* __restrict__ comb_w,
    const void* __restrict__ comb_b, const void* __restrict__ adj)
{
    const int f32 = probe_f32(adj);
    const int tid = blockIdx.x * 256 + threadIdx.x;
    const int nth = gridDim.x * 256;
    const int TOT = 98304 + 16384 * 3 + 32768 + 512 + 896;
    for (int e = tid; e < TOT; e += nth) {
        int i = e;
        if (i < 98304) {                                   // WT[k][g]
            const int k = i >> 9, g = i & 511;
            g_WT[i] = (k < 64) ? ldin(W_ih, (size_t)g * 64 + k, f32)
                               : ldin(W_hh, (size_t)g * 128 + (k - 64), f32);
            continue;
        }
        i -= 98304;
        if (i < 16384) { g_gcw[i] = ldin(gc_w, i, f32); continue; }
        i -= 16384;
        if (i < 16384) {                                   // WsT[k][o]
            const int k = i >> 7, o = i & 127;
            g_WsT[i] = ldin(Ws_w, (size_t)o * 128 + k, f32);
            continue;
        }
        i -= 16384;
        if (i < 16384) {
            const int k = i >> 7, o = i & 127;
            g_WtT[i] = ldin(Wt_w, (size_t)o * 128 + k, f32);
            continue;
        }
        i -= 16384;
        if (i < 32768) {                                   // combT[k][o]
            const int k = i >> 7, o = i & 127;
            g_combT[i] = ldin(comb_w, (size_t)o * 256 + k, f32);
            continue;
        }
        i -= 32768;
        if (i < 512) { g_bias[i] = ldin(b_ih, i, f32) + ldin(b_hh, i, f32); continue; }
        i -= 512;
        {
            const int seg = i >> 7, k = i & 127;
            const void* src = (seg == 0) ? gc_b : (seg == 1) ? Ws_b : (seg == 2) ? Wt_b :
                              (seg == 3) ? vvec : (seg == 4) ? ln_g : (seg == 5) ? ln_b : comb_b;
            g_svec[i] = ldin(src, k, f32);
        }
    }
}

// ---------------------------------------------------------------------------
// K1: 325 blocks x 512 threads, 4 nodes/block (R12 geometry) + fused adj
// compaction in the tail (writes g_nz/g_nzc so k2 skips the scan).
// ---------------------------------------------------------------------------
__global__ __launch_bounds__(512) void k1_lstm(
    const void* __restrict__ x, const void* __restrict__ h, const void* __restrict__ c,
    const void* __restrict__ adj, void* __restrict__ out)
{
    const int f32 = probe_f32(adj);
    __shared__ __align__(16) float4 xh4[192];    // [k] x {n0..n3}
    __shared__ __align__(16) float4 Gt4[512];    // [g] x {n0..n3}
    __shared__ __align__(16) float4 hl4[128];    // [k] x {n0..n3}
    __shared__ int cnt[4];
    const int node0 = blockIdx.x * 4;
    const int t = threadIdx.x;
    const int lane = t & 63, w = t >> 6;

    if (t < 4) cnt[t] = 0;
    for (int e = t; e < 768; e += 512) {
        const int n = e / 192, k = e % 192;
        const int node = node0 + n;
        ((float*)&xh4[k])[n] = (k < 64) ? ldin(x, (size_t)node * 64 + k, f32)
                                        : ldin(h, (size_t)node * 128 + (k - 64), f32);
    }
    __syncthreads();

    // gates: g = t; 192 coalesced weight loads, broadcast activations
    {
        const int g = t;
        float a0 = 0.f, a1 = 0.f, a2 = 0.f, a3 = 0.f;
        #pragma unroll 8
        for (int k = 0; k < 192; ++k) {
            const float wv = g_WT[(size_t)k * 512 + g];
            const float4 xv = xh4[k];
            a0 = fmaf(xv.x, wv, a0); a1 = fmaf(xv.y, wv, a1);
            a2 = fmaf(xv.z, wv, a2); a3 = fmaf(xv.w, wv, a3);
        }
        const float bias = g_bias[g];
        Gt4[g] = make_float4(a0 + bias, a1 + bias, a2 + bias, a3 + bias);
    }
    __syncthreads();

    // cell nonlinearity: t = (n, hh)
    {
        const int n = t >> 7, hh = t & 127;
        const int node = node0 + n;
        const float ig = ((const float*)&Gt4[hh])[n];
        const float fg = ((const float*)&Gt4[128 + hh])[n];
        const float gv = ((const float*)&Gt4[256 + hh])[n];
        const float og = ((const float*)&Gt4[384 + hh])[n];
        const float cl = sigm(fg) * ldin(c, (size_t)node * 128 + hh, f32) + sigm(ig) * tanh_f(gv);
        const float hv = sigm(og) * tanh_f(cl);
        stout(out, (size_t)(NODES * H_) + (size_t)node * 128 + hh, cl, f32);
        g_hl[(size_t)node * 128 + hh] = hv;
        ((float*)&hl4[hh])[n] = hv;
    }
    __syncthreads();

    // support[n][o] = sum_k hl[n][k] * gc_w[k][o]; coalesced gcw, broadcast hl
    {
        const int o = t & 127, n = t >> 7;       // n wave-uniform
        float acc = 0.f;
        #pragma unroll 8
        for (int k = 0; k < 128; ++k)
            acc = fmaf(((const float*)&hl4[k])[n], g_gcw[(size_t)k * 128 + o], acc);
        g_support[(size_t)(node0 + n) * 128 + o] = acc;
    }

    // fused adj compaction: waves w and w+4 split the row of node w&3
    {
        const int n = w & 3;
        const int node = node0 + n;
        const int j0 = (w >> 2) * 192;           // halves: [0,192) and [192,325)
        const int j1 = (w >> 2) ? N_ : 192;
        for (int j = j0 + lane; j < j1; j += 64) {
            float a = ldin(adj, (size_t)node * N_ + j, f32);
            if (a != 0.f) {
                int p = atomicAdd(&cnt[n], 1);
                if (p < NZMAX) g_nz[(size_t)node * NZMAX + p] = (u16)j;
            }
        }
    }
    __syncthreads();
    if (t < 4) g_nzc[node0 + t] = min(cnt[t], NZMAX);
}

// ---------------------------------------------------------------------------
// K2: 325 blocks x 256 threads, 4 nodes/block. nz load + gather + s/t proj.
// ---------------------------------------------------------------------------
__global__ __launch_bounds__(256) void k2_graph(const void* __restrict__ adj)
{
    const int f32 = probe_f32(adj);
    __shared__ __align__(16) float4 hg4[128];    // [k] x {n0..n3}
    __shared__ u16 nzi[4][NZMAX];
    __shared__ float nzv[4][NZMAX];
    __shared__ int cnt[4];
    const int node0 = blockIdx.x * 4;
    const int t = threadIdx.x;

    if (t < 4) cnt[t] = g_nzc[node0 + t];
    __syncthreads();
    #pragma unroll
    for (int n = 0; n < 4; ++n) {
        const int node = node0 + n;
        for (int p = t; p < cnt[n]; p += 256) {
            const u16 j = g_nz[(size_t)node * NZMAX + p];
            nzi[n][p] = j;
            nzv[n][p] = ldin(adj, (size_t)node * N_ + j, f32);
        }
    }
    __syncthreads();

    // h_graph gather (coalesced support rows)
    const int o = t & 127;
    const float gb = g_svec[o];                  // gc_b
    #pragma unroll
    for (int ps = 0; ps < 2; ++ps) {
        const int n = (t >> 7) + 2 * ps;
        const int node = node0 + n;
        const int bn = node / N_;
        const int cnn = cnt[n];
        float acc = gb;
        for (int p = 0; p < cnn; ++p)
            acc = fmaf(nzv[n][p], g_support[((size_t)bn * N_ + nzi[n][p]) * 128 + o], acc);
        g_h_graph[(size_t)node * 128 + o] = acc;
        ((float*)&hg4[o])[n] = acc;
    }
    __syncthreads();

    // s (t<128) / t (t>=128) projections: coalesced W^T, broadcast hg
    {
        const int which = t >> 7;
        const float* WT = which ? g_WtT : g_WsT;
        const float bias = g_svec[128 + which * 128 + o];
        float a0 = 0.f, a1 = 0.f, a2 = 0.f, a3 = 0.f;
        #pragma unroll 8
        for (int k = 0; k < 128; ++k) {
            const float wv = WT[(size_t)k * 128 + o];
            const float4 hv = hg4[k];
            a0 = fmaf(hv.x, wv, a0); a1 = fmaf(hv.y, wv, a1);
            a2 = fmaf(hv.z, wv, a2); a3 = fmaf(hv.w, wv, a3);
        }
        float* dst = which ? g_t_buf : g_s_buf;
        dst[(size_t)(node0 + 0) * 128 + o] = a0 + bias;
        dst[(size_t)(node0 + 1) * 128 + o] = a1 + bias;
        dst[(size_t)(node0 + 2) * 128 + o] = a2 + bias;
        dst[(size_t)(node0 + 3) * 128 + o] = a3 + bias;
    }
}

// ---------------------------------------------------------------------------
// K3: 325 blocks x 256 threads, 4 nodes/block (R12 exact).
// ---------------------------------------------------------------------------
__global__ __launch_bounds__(256) void k3_attn(
    const void* __restrict__ adj, void* __restrict__ out)
{
    const int f32 = probe_f32(adj);
    __shared__ __align__(16) float4 comb4[256];  // [k] x {n0..n3}: [h_lstm | h_att]
    __shared__ float s_i[4][H_];
    __shared__ float red[4][H_];
    __shared__ float nzs[4][NZMAX];
    __shared__ u16 nzi[4][NZMAX];
    __shared__ float part[2][4][H_];
    __shared__ float mu_[4], rstd_[4], smv[4];
    __shared__ int cnt[4];
    const int node0 = blockIdx.x * 4;
    const int t = threadIdx.x;
    const int lane = t & 63, w = t >> 6;

    if (t < 4) cnt[t] = g_nzc[node0 + t];
    for (int e = t; e < 512; e += 256) {
        const int n = e >> 7, k = e & 127;
        const int node = node0 + n;
        s_i[n][k] = g_s_buf[(size_t)node * 128 + k];
        ((float*)&comb4[k])[n] = g_hl[(size_t)node * 128 + k];
    }
    __syncthreads();
    #pragma unroll
    for (int n = 0; n < 4; ++n)
        for (int p = t; p < cnt[n]; p += 256) nzi[n][p] = g_nz[(size_t)(node0 + n) * NZMAX + p];
    __syncthreads();

    // scores: wave w owns node node0+w; lane covers dims lane, lane+64
    {
        const int bn = (node0 + w) / N_;
        const int cn = cnt[w];
        const float v0 = g_svec[384 + lane], v1 = g_svec[384 + 64 + lane];
        const float si0 = s_i[w][lane], si1 = s_i[w][lane + 64];
        for (int p = 0; p < cn; ++p) {
            const float* tj = g_t_buf + ((size_t)bn * N_ + nzi[w][p]) * 128;
            float a = v0 * tanh_f(si0 + tj[lane]) + v1 * tanh_f(si1 + tj[lane + 64]);
            #pragma unroll
            for (int off = 32; off > 0; off >>= 1) a += __shfl_xor(a, off);
            if (lane == 0) nzs[w][p] = a;
        }
    }
    __syncthreads();

    if (t < 4) {                                 // softmax (serial, ~17-35)
        const int cn = cnt[t];
        float m = -1e30f;
        for (int p = 0; p < cn; ++p) m = fmaxf(m, nzs[t][p]);
        float ssum = 0.f;
        for (int p = 0; p < cn; ++p) { float e = __expf(nzs[t][p] - m); nzs[t][p] = e; ssum += e; }
        smv[t] = fast_rcp(ssum);
    }
    __syncthreads();

    // context (coalesced h_graph rows)
    const int o = t & 127;
    #pragma unroll
    for (int ps = 0; ps < 2; ++ps) {
        const int n = (t >> 7) + 2 * ps;
        const int bn = (node0 + n) / N_;
        const int cn = cnt[n];
        float acc = 0.f;
        for (int p = 0; p < cn; ++p)
            acc = fmaf(nzs[n][p], g_h_graph[((size_t)bn * N_ + nzi[n][p]) * 128 + o], acc);
        red[n][o] = acc * smv[n];
    }
    __syncthreads();

    // LayerNorm stats: wave w -> node w
    {
        float x0 = red[w][lane], x1 = red[w][lane + 64];
        float sm = x0 + x1, sq = x0 * x0 + x1 * x1;
        #pragma unroll
        for (int off = 32; off > 0; off >>= 1) {
            sm += __shfl_xor(sm, off);
            sq += __shfl_xor(sq, off);
        }
        if (lane == 0) {
            float mu = sm * (1.f / H_);
            float var = fmaxf(sq * (1.f / H_) - mu * mu, 0.f);
            mu_[w] = mu;
            rstd_[w] = __builtin_amdgcn_rsqf(var + 1e-5f);
        }
    }
    __syncthreads();
    for (int e = t; e < 512; e += 256) {
        const int n = e >> 7, k = e & 127;
        float xn = (red[n][k] - mu_[n]) * rstd_[n];
        ((float*)&comb4[128 + k])[n] = g_svec[512 + k] * xn + g_svec[640 + k];
    }
    __syncthreads();

    // combine: coalesced combT, broadcast comb4; k split over halves
    {
        const int half = t >> 7;
        float a0 = 0.f, a1 = 0.f, a2 = 0.f, a3 = 0.f;
        const int k0 = half * 128;
        #pragma unroll 8
        for (int kk = 0; kk < 128; ++kk) {
            const float wv = g_combT[(size_t)(k0 + kk) * 128 + o];
            const float4 cv = comb4[k0 + kk];
            a0 = fmaf(cv.x, wv, a0); a1 = fmaf(cv.y, wv, a1);
            a2 = fmaf(cv.z, wv, a2); a3 = fmaf(cv.w, wv, a3);
        }
        part[half][0][o] = a0; part[half][1][o] = a1;
        part[half][2][o] = a2; part[half][3][o] = a3;
    }
    __syncthreads();
    for (int e = t; e < 512; e += 256) {
        const int n = e >> 7, k = e & 127;
        stout(out, (size_t)(node0 + n) * 128 + k,
              part[0][n][k] + part[1][n][k] + g_svec[768 + k], f32);
    }
}

// ---------------------------------------------------------------------------
extern "C" void kernel_launch(void* const* d_in, const int* in_sizes, int n_in,
                              void* d_out, int out_size, void* d_ws, size_t ws_size,
                              hipStream_t stream)
{
    (void)in_sizes; (void)n_in; (void)out_size; (void)d_ws; (void)ws_size;
    const void* x      = d_in[0];
    const void* adj    = d_in[1];
    const void* h      = d_in[2];
    const void* c      = d_in[3];
    const void* W_ih   = d_in[4];
    const void* W_hh   = d_in[5];
    const void* b_ih   = d_in[6];
    const void* b_hh   = d_in[7];
    const void* gc_w   = d_in[8];
    const void* gc_b   = d_in[9];
    const void* Ws_w   = d_in[10];
    const void* Ws_b   = d_in[11];
    const void* Wt_w   = d_in[12];
    const void* Wt_b   = d_in[13];
    const void* vvec   = d_in[14];
    const void* ln_g   = d_in[15];
    const void* ln_b   = d_in[16];
    const void* comb_w = d_in[17];
    const void* comb_b = d_in[18];

    k0_prep <<<256, 256, 0, stream>>>(W_ih, W_hh, b_ih, b_hh, gc_w, gc_b,
                                      Ws_w, Ws_b, Wt_w, Wt_b, vvec, ln_g, ln_b,
                                      comb_w, comb_b, adj);
    k1_lstm <<<NODES / 4, 512, 0, stream>>>(x, h, c, adj, d_out);
    k2_graph<<<NODES / 4, 256, 0, stream>>>(adj);
    k3_attn <<<NODES / 4, 256, 0, stream>>>(adj, d_out);
}